// Round 2
// baseline (496.595 us; speedup 1.0000x reference)
//
#include <hip/hip_runtime.h>
#include <math.h>

typedef short short8 __attribute__((ext_vector_type(8)));
typedef float floatx4 __attribute__((ext_vector_type(4)));

#define TEMP_INV 5.0f
#define W_UNSUP 0.2f
#define NB_BCE 256

static __device__ __forceinline__ unsigned short f2bf(float f) {
  unsigned int u = __float_as_uint(f);
  u += 0x7FFFu + ((u >> 16) & 1u);
  return (unsigned short)(u >> 16);
}

__device__ __forceinline__ float block_sum256(float v) {
  __shared__ float sh[4];
  for (int m = 1; m <= 32; m <<= 1) v += __shfl_xor(v, m);
  __syncthreads();
  if ((threadIdx.x & 63) == 0) sh[threadIdx.x >> 6] = v;
  __syncthreads();
  return sh[0] + sh[1] + sh[2] + sh[3];
}

// Detect train_mask storage: 0 = int32 {0,1}, 1 = float32 {0,1.0f}, 2 = raw bytes
__global__ void detect_kernel(const unsigned int* __restrict__ w, int nw, int* __restrict__ flag) {
  __shared__ int s_int, s_flt;
  if (threadIdx.x == 0) { s_int = 1; s_flt = 1; }
  __syncthreads();
  for (int i = threadIdx.x; i < nw; i += blockDim.x) {
    unsigned int x = w[i];
    if (x != 0u && x != 1u) s_int = 0;
    if (x != 0u && x != 0x3F800000u) s_flt = 0;
  }
  __syncthreads();
  if (threadIdx.x == 0) *flag = s_int ? 0 : (s_flt ? 1 : 2);
}

__global__ __launch_bounds__(256) void bce_kernel(
    const float* __restrict__ fused, const float* __restrict__ viewl,
    const float* __restrict__ labels, const void* __restrict__ maskp,
    const int* __restrict__ flagp, float* __restrict__ partials, int N, int V) {
  const int flag = *flagp;
  float cnt = 0.f, sm = 0.f;
  float sv[8];
  for (int v = 0; v < 8; v++) sv[v] = 0.f;
  const int Vc = V > 8 ? 8 : V;
  for (int i = blockIdx.x * blockDim.x + threadIdx.x; i < N; i += gridDim.x * blockDim.x) {
    bool m;
    if (flag == 0)      m = ((const int*)maskp)[i] != 0;
    else if (flag == 1) m = ((const float*)maskp)[i] != 0.0f;
    else                m = ((const unsigned char*)maskp)[i] != 0;
    if (!m) continue;
    float y = labels[i];
    cnt += 1.0f;
    float x = fused[i];
    sm += fmaxf(x, 0.f) - x * y + log1pf(__expf(-fabsf(x)));
    for (int v = 0; v < Vc; v++) {
      float xv = viewl[(size_t)v * N + i];
      sv[v] += fmaxf(xv, 0.f) - xv * y + log1pf(__expf(-fabsf(xv)));
    }
  }
  float tot = block_sum256(cnt);
  if (threadIdx.x == 0) partials[blockIdx.x * 16 + 0] = tot;
  tot = block_sum256(sm);
  if (threadIdx.x == 0) partials[blockIdx.x * 16 + 1] = tot;
  for (int v = 0; v < Vc; v++) {
    tot = block_sum256(sv[v]);
    if (threadIdx.x == 0) partials[blockIdx.x * 16 + 2 + v] = tot;
  }
}

// Gather rows into bf16 matrices (8 rows/block, 32 lanes/row, 8 elems/lane).
// Also zero-init the atomic E/B accumulators used by sim_kernel.
__global__ __launch_bounds__(256) void gather_kernel(
    const float* __restrict__ proj, const int* __restrict__ pos_idx,
    const int* __restrict__ neg_idx, const int* __restrict__ unl_idx,
    unsigned short* __restrict__ zsup, unsigned short* __restrict__ zuns,
    float* __restrict__ dsup, float* __restrict__ duns,
    float* __restrict__ Esup, float* __restrict__ Bsup,
    float* __restrict__ Euns, float* __restrict__ Buns,
    int N, int D, int V, int P, int Msup, int Muns) {
  const int prob = blockIdx.y;
  const int M = prob ? Muns : Msup;
  const int r0 = blockIdx.x * 8;
  const int t = threadIdx.x;
  if (t < 8) {
    int rz = r0 + t;
    if (rz < M) {
      if (prob) { Euns[rz] = 0.f; Buns[rz] = 0.f; }
      else      { Esup[rz] = 0.f; Bsup[rz] = 0.f; }
    }
  }
  const int sub = t >> 5, ln = t & 31;
  const int r = r0 + sub;
  if (r >= M) return;
  const int l = r / V, v = r - l * V;
  const int idx = prob ? unl_idx[l] : (l < P ? pos_idx[l] : neg_idx[l - P]);
  const float* src = proj + ((size_t)v * N + (size_t)idx) * D + ln * 8;
  floatx4 p0 = *(const floatx4*)(src);
  floatx4 p1 = *(const floatx4*)(src + 4);
  float s = 0.f;
#pragma unroll
  for (int k = 0; k < 4; k++) s += p0[k] * p0[k] + p1[k] * p1[k];
  // reduce over the 32 lanes of this row (masks 1..16 stay inside the 32-group)
  for (int m = 1; m <= 16; m <<= 1) s += __shfl_xor(s, m);
  const float n2 = s;
  float sc = 1.0f, dval = n2 * TEMP_INV;
  if (prob) {
    sc = 1.0f / (sqrtf(n2) + 1e-8f);
    dval = n2 * sc * sc * TEMP_INV;
  }
  short8 vv;
#pragma unroll
  for (int k = 0; k < 4; k++) {
    vv[k]     = (short)f2bf(p0[k] * sc);
    vv[k + 4] = (short)f2bf(p1[k] * sc);
  }
  unsigned short* zd = prob ? zuns : zsup;
  *(short8*)(zd + (size_t)r * 256 + ln * 8) = vv;
  if (ln == 0) (prob ? duns : dsup)[r] = dval;
}

// Symmetric sim kernel: one 64x64 tile per block, upper-triangle strip pairs only.
// sim = Z Z^T / temp is symmetric, and both E (row-sum of exp) and B (positive-
// block sum) use symmetric predicates, so each off-diagonal element contributes
// identically to its row anchor and its column anchor.
// 4 waves, each 32 rows x 32 cols (2x2 sub-tiles of 16x16x32 MFMA): every
// B-fragment ds_read feeds 2 MFMAs, halving LDS read traffic vs 16-row waves.
__global__ __launch_bounds__(256) void sim_kernel(
    const unsigned short* __restrict__ zsup, const unsigned short* __restrict__ zuns,
    float* __restrict__ Esup, float* __restrict__ Bsup,
    float* __restrict__ Euns, float* __restrict__ Buns,
    int Msup, int Muns, int PV, int V,
    int Tsup, int Tuns, int nsSup, int nsUns) {
  const int prob = blockIdx.y;
  const unsigned short* __restrict__ z = prob ? zuns : zsup;
  float* __restrict__ Ep = prob ? Euns : Esup;
  float* __restrict__ Bp = prob ? Buns : Bsup;
  const int M = prob ? Muns : Msup;
  const int ns = prob ? nsUns : nsSup;
  const int T = prob ? Tuns : Tsup;
  const int t = blockIdx.x;
  if (t >= T) return;

  // map linear t -> (si, sj), 0 <= si <= sj < ns
#define TRI_BASE(s) ((s) * ns - ((s) * ((s) - 1)) / 2)
  int si = (int)((2.0f * ns + 1.0f -
                  sqrtf((2.0f * ns + 1.0f) * (2.0f * ns + 1.0f) - 8.0f * (float)t)) * 0.5f);
  if (si < 0) si = 0;
  if (si > ns - 1) si = ns - 1;
  while (si > 0 && TRI_BASE(si) > t) si--;
  while (si < ns - 1 && TRI_BASE(si + 1) <= t) si++;
  const int sj = si + (t - TRI_BASE(si));
#undef TRI_BASE

  const int R0 = si * 64, C0 = sj * 64;
  const int tid = threadIdx.x;
  const int wave = tid >> 6;
  const int wr = wave >> 1, wc = wave & 1;     // row-half / col-half of the 64x64 tile
  const int q = (tid >> 4) & 3;
  const int n16 = tid & 15;

  // 64 col rows x 256 k, +8 bf16 pad per row -> ds_read_b128 is 2-way (free)
  __shared__ __align__(16) unsigned short lds[64 * 264];
  __shared__ float redRE[64], redRB[64], redCE[64], redCB[64];

  // stage column strip [C0, C0+64) into LDS
#pragma unroll
  for (int cc = 0; cc < 8; cc++) {
    int chunk = cc * 256 + tid;
    int rrow = chunk >> 5;
    int off = (chunk & 31) * 8;
    int gcol = C0 + rrow;
    short8 vv = {0, 0, 0, 0, 0, 0, 0, 0};
    if (gcol < M) vv = *(const short8*)(z + (size_t)gcol * 256 + off);
    *(short8*)(&lds[rrow * 264 + off]) = vv;
  }
  if (tid < 64) { redRE[tid] = 0.f; redRB[tid] = 0.f; redCE[tid] = 0.f; redCB[tid] = 0.f; }

  // A fragments: 2 sets of 16 rows (this wave's 32 rows), K=256 in registers
  short8 a[2][8];
#pragma unroll
  for (int m = 0; m < 2; m++) {
    int row = R0 + wr * 32 + m * 16 + n16;
    if (row >= M) row = M - 1;
    const unsigned short* zr = z + (size_t)row * 256 + q * 8;
#pragma unroll
    for (int ks = 0; ks < 8; ks++) a[m][ks] = *(const short8*)(zr + ks * 32);
  }

  // positive-block bounds per output row (symmetric predicate)
  int bs[2][4], be[2][4];
#pragma unroll
  for (int m = 0; m < 2; m++)
#pragma unroll
    for (int r = 0; r < 4; r++) {
      int row = R0 + wr * 32 + m * 16 + q * 4 + r;
      if (row >= M) row = M - 1;
      if (prob == 0) { bs[m][r] = row < PV ? 0 : PV; be[m][r] = row < PV ? PV : M; }
      else           { int b0 = (row / V) * V; bs[m][r] = b0; be[m][r] = b0 + V; }
    }

  __syncthreads();

  floatx4 acc00 = {0.f, 0.f, 0.f, 0.f}, acc01 = {0.f, 0.f, 0.f, 0.f};
  floatx4 acc10 = {0.f, 0.f, 0.f, 0.f}, acc11 = {0.f, 0.f, 0.f, 0.f};
#pragma unroll
  for (int ks = 0; ks < 8; ks++) {
    const unsigned short* bp = &lds[(wc * 32 + n16) * 264 + q * 8 + ks * 32];
    short8 b0 = *(const short8*)bp;
    short8 b1 = *(const short8*)(bp + 16 * 264);
    acc00 = __builtin_amdgcn_mfma_f32_16x16x32_bf16(a[0][ks], b0, acc00, 0, 0, 0);
    acc01 = __builtin_amdgcn_mfma_f32_16x16x32_bf16(a[0][ks], b1, acc01, 0, 0, 0);
    acc10 = __builtin_amdgcn_mfma_f32_16x16x32_bf16(a[1][ks], b0, acc10, 0, 0, 0);
    acc11 = __builtin_amdgcn_mfma_f32_16x16x32_bf16(a[1][ks], b1, acc11, 0, 0, 0);
  }

  float er0[4] = {0, 0, 0, 0}, er1[4] = {0, 0, 0, 0};
  float br0[4] = {0, 0, 0, 0}, br1[4] = {0, 0, 0, 0};
  float ec0 = 0.f, ec1 = 0.f, bc0 = 0.f, bc1 = 0.f;
  const int j0 = C0 + wc * 32 + n16;
  const int j1 = j0 + 16;

#define EPI(ACC, MM, JN, ECOL, BCOL, ERA, BRA)                        \
  _Pragma("unroll")                                                   \
  for (int r = 0; r < 4; r++) {                                       \
    int row = R0 + wr * 32 + MM * 16 + q * 4 + r;                     \
    float tv = ACC[r] * TEMP_INV;                                     \
    bool valid = (row < M) && (JN < M);                               \
    float e = valid ? __expf(tv - 5.0f) : 0.0f;                       \
    float bv = (valid && JN >= bs[MM][r] && JN < be[MM][r]) ? tv : 0.0f; \
    ERA[r] += e; BRA[r] += bv; ECOL += e; BCOL += bv;                 \
  }
  EPI(acc00, 0, j0, ec0, bc0, er0, br0)
  EPI(acc01, 0, j1, ec1, bc1, er0, br0)
  EPI(acc10, 1, j0, ec0, bc0, er1, br1)
  EPI(acc11, 1, j1, ec1, bc1, er1, br1)
#undef EPI

  // row sums: reduce over the 16 n16-lanes, combine col-half waves in LDS
#pragma unroll
  for (int mr = 0; mr < 8; mr++) {
    const int m = mr >> 2, r = mr & 3;
    float e = m ? er1[r] : er0[r];
    float b = m ? br1[r] : br0[r];
    for (int msk = 1; msk <= 8; msk <<= 1) { e += __shfl_xor(e, msk); b += __shfl_xor(b, msk); }
    if (n16 == 0) {
      int lr = wr * 32 + m * 16 + q * 4 + r;
      atomicAdd(&redRE[lr], e);
      atomicAdd(&redRB[lr], b);
    }
  }
  // col sums (off-diagonal tiles only): reduce over q, combine row-half waves
  if (si != sj) {
    float e = ec0, b = bc0;
    e += __shfl_xor(e, 16); e += __shfl_xor(e, 32);
    b += __shfl_xor(b, 16); b += __shfl_xor(b, 32);
    if (q == 0) { atomicAdd(&redCE[wc * 32 + n16], e); atomicAdd(&redCB[wc * 32 + n16], b); }
    e = ec1; b = bc1;
    e += __shfl_xor(e, 16); e += __shfl_xor(e, 32);
    b += __shfl_xor(b, 16); b += __shfl_xor(b, 32);
    if (q == 0) { atomicAdd(&redCE[wc * 32 + 16 + n16], e); atomicAdd(&redCB[wc * 32 + 16 + n16], b); }
  }

  __syncthreads();
  if (tid < 64) {
    int row = R0 + tid;
    if (row < M) { atomicAdd(&Ep[row], redRE[tid]); atomicAdd(&Bp[row], redRB[tid]); }
    if (si != sj) {
      int col = C0 + tid;
      if (col < M) { atomicAdd(&Ep[col], redCE[tid]); atomicAdd(&Bp[col], redCB[tid]); }
    }
  }
}

__global__ __launch_bounds__(256) void finalize_kernel(
    const float* __restrict__ partials,
    const float* __restrict__ Esup, const float* __restrict__ Bsup, const float* __restrict__ dsup,
    const float* __restrict__ Euns, const float* __restrict__ Buns, const float* __restrict__ duns,
    int Msup, int Muns, int PV, int P, int NEG, int V, float* __restrict__ out) {
  const int t = threadIdx.x;
  float cnt = 0.f, sm = 0.f, sv[8];
  for (int v = 0; v < 8; v++) sv[v] = 0.f;
  const int Vc = V > 8 ? 8 : V;
  for (int b = t; b < NB_BCE; b += 256) {
    cnt += partials[b * 16 + 0];
    sm  += partials[b * 16 + 1];
    for (int v = 0; v < Vc; v++) sv[v] += partials[b * 16 + 2 + v];
  }
  cnt = block_sum256(cnt);
  sm = block_sum256(sm);
  float svt = 0.f;
  for (int v = 0; v < Vc; v++) svt += block_sum256(sv[v]);
  const float denomC = fmaxf(cnt, 1.0f);
  const float main_loss = sm / denomC;
  const float view_loss = (svt / denomC) / (float)V;

  // sup: per-anchor = log(E - exp(d-5)) + 5 - (B - d)/pos_count
  float ssup = 0.f;
  for (int row = t; row < Msup; row += 256) {
    float E = Esup[row], B = Bsup[row];
    float d = dsup[row];
    float dn = E - __expf(d - 5.0f);
    float cl = (row < PV) ? (float)P : (float)NEG;
    float pc = (float)(V - 1) + (cl - 1.0f) * (float)V;
    ssup += logf(dn) + 5.0f - (B - d) / pc;
  }
  ssup = block_sum256(ssup);
  const float sup_loss = ssup / (float)Msup;

  // unsup: per-anchor = log(E - exp(d-5)) + 5 - (B - d)/(V-1)
  float suns = 0.f;
  for (int row = t; row < Muns; row += 256) {
    float E = Euns[row], B = Buns[row];
    float d = duns[row];
    float dn = E - __expf(d - 5.0f);
    suns += logf(dn) + 5.0f - (B - d) / (float)(V - 1);
  }
  suns = block_sum256(suns);
  const float unsup_loss = suns / (float)Muns;

  if (t == 0) {
    float total = main_loss + view_loss + sup_loss + W_UNSUP * unsup_loss;
    out[0] = total;
    out[1] = main_loss;
    out[2] = view_loss;
    out[3] = sup_loss;
    out[4] = unsup_loss;
  }
}

extern "C" void kernel_launch(void* const* d_in, const int* in_sizes, int n_in,
                              void* d_out, int out_size, void* d_ws, size_t ws_size,
                              hipStream_t stream) {
  const float* fused  = (const float*)d_in[0];
  const float* viewl  = (const float*)d_in[1];
  const float* proj   = (const float*)d_in[2];
  const float* labels = (const float*)d_in[3];
  const void*  maskp  = d_in[4];
  const int* pos_idx  = (const int*)d_in[5];
  const int* neg_idx  = (const int*)d_in[6];
  const int* unl_idx  = (const int*)d_in[7];

  const int N = in_sizes[0];
  const int V = in_sizes[1] / N;
  const int D = in_sizes[2] / in_sizes[1];   // = 256
  const int P = in_sizes[5];
  const int NEG = in_sizes[6];
  const int U = in_sizes[7];
  const int L = P + NEG;
  const int Msup = L * V;
  const int Muns = U * V;
  const int PV = P * V;

  char* ws = (char*)d_ws;
  size_t off = 0;
  auto alloc = [&](size_t bytes) { size_t o = off; off += (bytes + 255) & ~(size_t)255; return o; };
  const size_t o_flag = alloc(4);
  const size_t o_part = alloc((size_t)NB_BCE * 16 * 4);
  const size_t o_zsup = alloc((size_t)Msup * D * 2);
  const size_t o_zuns = alloc((size_t)Muns * D * 2);
  const size_t o_dsup = alloc((size_t)Msup * 4);
  const size_t o_duns = alloc((size_t)Muns * 4);
  const size_t o_Esup = alloc((size_t)Msup * 4);
  const size_t o_Bsup = alloc((size_t)Msup * 4);
  const size_t o_Euns = alloc((size_t)Muns * 4);
  const size_t o_Buns = alloc((size_t)Muns * 4);

  int* flag = (int*)(ws + o_flag);
  float* partials = (float*)(ws + o_part);
  unsigned short* zsup = (unsigned short*)(ws + o_zsup);
  unsigned short* zuns = (unsigned short*)(ws + o_zuns);
  float* dsup = (float*)(ws + o_dsup);
  float* duns = (float*)(ws + o_duns);
  float* Esup = (float*)(ws + o_Esup);
  float* Bsup = (float*)(ws + o_Bsup);
  float* Euns = (float*)(ws + o_Euns);
  float* Buns = (float*)(ws + o_Buns);

  int nw = N / 4 < 256 ? N / 4 : 256;
  detect_kernel<<<1, 256, 0, stream>>>((const unsigned int*)maskp, nw, flag);
  bce_kernel<<<NB_BCE, 256, 0, stream>>>(fused, viewl, labels, maskp, flag, partials, N, V);

  const int Mmax = Msup > Muns ? Msup : Muns;
  dim3 ggrid((Mmax + 7) / 8, 2);
  gather_kernel<<<ggrid, 256, 0, stream>>>(proj, pos_idx, neg_idx, unl_idx,
                                           zsup, zuns, dsup, duns,
                                           Esup, Bsup, Euns, Buns,
                                           N, D, V, P, Msup, Muns);

  const int nsS = (Msup + 63) / 64;
  const int nsU = (Muns + 63) / 64;
  const int Ts = nsS * (nsS + 1) / 2;
  const int Tu = nsU * (nsU + 1) / 2;
  const int Tmax = Ts > Tu ? Ts : Tu;
  dim3 sgrid(Tmax, 2);
  sim_kernel<<<sgrid, 256, 0, stream>>>(zsup, zuns, Esup, Bsup, Euns, Buns,
                                        Msup, Muns, PV, V, Ts, Tu, nsS, nsU);

  finalize_kernel<<<1, 256, 0, stream>>>(partials, Esup, Bsup, dsup, Euns, Buns, duns,
                                         Msup, Muns, PV, P, NEG, V, (float*)d_out);
}

// Round 3
// 463.413 us; speedup vs baseline: 1.0716x; 1.0716x over previous
//
#include <hip/hip_runtime.h>
#include <math.h>

typedef short short8 __attribute__((ext_vector_type(8)));
typedef float floatx4 __attribute__((ext_vector_type(4)));

#define TEMP_INV 5.0f
#define W_UNSUP 0.2f
#define NB_BCE 256
#define NSPLIT 8

static __device__ __forceinline__ unsigned short f2bf(float f) {
  unsigned int u = __float_as_uint(f);
  u += 0x7FFFu + ((u >> 16) & 1u);
  return (unsigned short)(u >> 16);
}

__device__ __forceinline__ float block_sum256(float v) {
  __shared__ float sh[4];
  for (int m = 1; m <= 32; m <<= 1) v += __shfl_xor(v, m);
  __syncthreads();
  if ((threadIdx.x & 63) == 0) sh[threadIdx.x >> 6] = v;
  __syncthreads();
  return sh[0] + sh[1] + sh[2] + sh[3];
}

// Detect train_mask storage: 0 = int32 {0,1}, 1 = float32 {0,1.0f}, 2 = raw bytes
__global__ void detect_kernel(const unsigned int* __restrict__ w, int nw, int* __restrict__ flag) {
  __shared__ int s_int, s_flt;
  if (threadIdx.x == 0) { s_int = 1; s_flt = 1; }
  __syncthreads();
  for (int i = threadIdx.x; i < nw; i += blockDim.x) {
    unsigned int x = w[i];
    if (x != 0u && x != 1u) s_int = 0;
    if (x != 0u && x != 0x3F800000u) s_flt = 0;
  }
  __syncthreads();
  if (threadIdx.x == 0) *flag = s_int ? 0 : (s_flt ? 1 : 2);
}

__global__ __launch_bounds__(256) void bce_kernel(
    const float* __restrict__ fused, const float* __restrict__ viewl,
    const float* __restrict__ labels, const void* __restrict__ maskp,
    const int* __restrict__ flagp, float* __restrict__ partials, int N, int V) {
  const int flag = *flagp;
  float cnt = 0.f, sm = 0.f;
  float sv[8];
  for (int v = 0; v < 8; v++) sv[v] = 0.f;
  const int Vc = V > 8 ? 8 : V;
  for (int i = blockIdx.x * blockDim.x + threadIdx.x; i < N; i += gridDim.x * blockDim.x) {
    bool m;
    if (flag == 0)      m = ((const int*)maskp)[i] != 0;
    else if (flag == 1) m = ((const float*)maskp)[i] != 0.0f;
    else                m = ((const unsigned char*)maskp)[i] != 0;
    if (!m) continue;
    float y = labels[i];
    cnt += 1.0f;
    float x = fused[i];
    sm += fmaxf(x, 0.f) - x * y + log1pf(__expf(-fabsf(x)));
    for (int v = 0; v < Vc; v++) {
      float xv = viewl[(size_t)v * N + i];
      sv[v] += fmaxf(xv, 0.f) - xv * y + log1pf(__expf(-fabsf(xv)));
    }
  }
  float tot = block_sum256(cnt);
  if (threadIdx.x == 0) partials[blockIdx.x * 16 + 0] = tot;
  tot = block_sum256(sm);
  if (threadIdx.x == 0) partials[blockIdx.x * 16 + 1] = tot;
  for (int v = 0; v < Vc; v++) {
    tot = block_sum256(sv[v]);
    if (threadIdx.x == 0) partials[blockIdx.x * 16 + 2 + v] = tot;
  }
}

// Gather rows into bf16 matrices (8 rows/block, 32 lanes/row, 8 elems/lane).
// Also zero-init the atomic E/B accumulators used by sim_kernel.
__global__ __launch_bounds__(256) void gather_kernel(
    const float* __restrict__ proj, const int* __restrict__ pos_idx,
    const int* __restrict__ neg_idx, const int* __restrict__ unl_idx,
    unsigned short* __restrict__ zsup, unsigned short* __restrict__ zuns,
    float* __restrict__ dsup, float* __restrict__ duns,
    float* __restrict__ Esup, float* __restrict__ Bsup,
    float* __restrict__ Euns, float* __restrict__ Buns,
    int N, int D, int V, int P, int Msup, int Muns) {
  const int prob = blockIdx.y;
  const int M = prob ? Muns : Msup;
  const int r0 = blockIdx.x * 8;
  const int t = threadIdx.x;
  if (t < 8) {
    int rz = r0 + t;
    if (rz < M) {
      if (prob) { Euns[rz] = 0.f; Buns[rz] = 0.f; }
      else      { Esup[rz] = 0.f; Bsup[rz] = 0.f; }
    }
  }
  const int sub = t >> 5, ln = t & 31;
  const int r = r0 + sub;
  if (r >= M) return;
  const int l = r / V, v = r - l * V;
  const int idx = prob ? unl_idx[l] : (l < P ? pos_idx[l] : neg_idx[l - P]);
  const float* src = proj + ((size_t)v * N + (size_t)idx) * D + ln * 8;
  floatx4 p0 = *(const floatx4*)(src);
  floatx4 p1 = *(const floatx4*)(src + 4);
  float s = 0.f;
#pragma unroll
  for (int k = 0; k < 4; k++) s += p0[k] * p0[k] + p1[k] * p1[k];
  // reduce over the 32 lanes of this row (masks 1..16 stay inside the 32-group)
  for (int m = 1; m <= 16; m <<= 1) s += __shfl_xor(s, m);
  const float n2 = s;
  float sc = 1.0f, dval = n2 * TEMP_INV;
  if (prob) {
    sc = 1.0f / (sqrtf(n2) + 1e-8f);
    dval = n2 * sc * sc * TEMP_INV;
  }
  short8 vv;
#pragma unroll
  for (int k = 0; k < 4; k++) {
    vv[k]     = (short)f2bf(p0[k] * sc);
    vv[k + 4] = (short)f2bf(p1[k] * sc);
  }
  unsigned short* zd = prob ? zuns : zsup;
  *(short8*)(zd + (size_t)r * 256 + ln * 8) = vv;
  if (ln == 0) (prob ? duns : dsup)[r] = dval;
}

// Symmetric sim kernel, A-amortized: block = (row strip si, col split s).
// The block loads its 64-row A strip ONCE into registers and walks column
// tiles tj = si+s, si+s+NSPLIT, ... < ns (upper triangle only). Row E/B
// accumulate in registers across tiles (one flush per block); column E/B
// (the symmetric counterpart of each off-diagonal tile) are q-reduced and
// flushed per tile via global atomicAdd. Diagonal tile: rows only.
// 4 waves, each 32 rows x 32 cols (2x2 sub-tiles of 16x16x32 MFMA).
__global__ __launch_bounds__(256) void sim_kernel(
    const unsigned short* __restrict__ zsup, const unsigned short* __restrict__ zuns,
    float* __restrict__ Esup, float* __restrict__ Bsup,
    float* __restrict__ Euns, float* __restrict__ Buns,
    int Msup, int Muns, int PV, int V, int nsSup, int nsUns) {
  const int prob = blockIdx.y;
  const unsigned short* __restrict__ z = prob ? zuns : zsup;
  float* __restrict__ Ep = prob ? Euns : Esup;
  float* __restrict__ Bp = prob ? Buns : Bsup;
  const int M = prob ? Muns : Msup;
  const int ns = prob ? nsUns : nsSup;

  const int si = blockIdx.x / NSPLIT;
  const int s  = blockIdx.x - si * NSPLIT;
  if (si >= ns) return;

  const int R0 = si * 64;
  const int tid = threadIdx.x;
  const int wave = tid >> 6;
  const int wr = wave >> 1, wc = wave & 1;     // row-half / col-half of the 64x64 tile
  const int q = (tid >> 4) & 3;
  const int n16 = tid & 15;

  // 64 col rows x 256 k, +8 bf16 pad per row -> ds_read_b128 is 2-way (free)
  __shared__ __align__(16) unsigned short lds[64 * 264];

  // A fragments: 2 sets of 16 rows (this wave's 32 rows), K=256 in registers
  short8 a[2][8];
#pragma unroll
  for (int m = 0; m < 2; m++) {
    int row = R0 + wr * 32 + m * 16 + n16;
    if (row >= M) row = M - 1;
    const unsigned short* zr = z + (size_t)row * 256 + q * 8;
#pragma unroll
    for (int ks = 0; ks < 8; ks++) a[m][ks] = *(const short8*)(zr + ks * 32);
  }

  // positive-block bounds per output row (symmetric predicate)
  int bs[2][4], be[2][4];
#pragma unroll
  for (int m = 0; m < 2; m++)
#pragma unroll
    for (int r = 0; r < 4; r++) {
      int row = R0 + wr * 32 + m * 16 + q * 4 + r;
      if (row >= M) row = M - 1;
      if (prob == 0) { bs[m][r] = row < PV ? 0 : PV; be[m][r] = row < PV ? PV : M; }
      else           { int b0 = (row / V) * V; bs[m][r] = b0; be[m][r] = b0 + V; }
    }

  // row accumulators persist across all tiles of this block
  float er0[4] = {0, 0, 0, 0}, er1[4] = {0, 0, 0, 0};
  float br0[4] = {0, 0, 0, 0}, br1[4] = {0, 0, 0, 0};

  for (int tj = si + s; tj < ns; tj += NSPLIT) {
    const int C0 = tj * 64;
    __syncthreads();
    // stage column strip [C0, C0+64) into LDS
#pragma unroll
    for (int cc = 0; cc < 8; cc++) {
      int chunk = cc * 256 + tid;
      int rrow = chunk >> 5;
      int off = (chunk & 31) * 8;
      int gcol = C0 + rrow;
      short8 vv = {0, 0, 0, 0, 0, 0, 0, 0};
      if (gcol < M) vv = *(const short8*)(z + (size_t)gcol * 256 + off);
      *(short8*)(&lds[rrow * 264 + off]) = vv;
    }
    __syncthreads();

    floatx4 acc00 = {0.f, 0.f, 0.f, 0.f}, acc01 = {0.f, 0.f, 0.f, 0.f};
    floatx4 acc10 = {0.f, 0.f, 0.f, 0.f}, acc11 = {0.f, 0.f, 0.f, 0.f};
#pragma unroll
    for (int ks = 0; ks < 8; ks++) {
      const unsigned short* bp = &lds[(wc * 32 + n16) * 264 + q * 8 + ks * 32];
      short8 b0 = *(const short8*)bp;
      short8 b1 = *(const short8*)(bp + 16 * 264);
      acc00 = __builtin_amdgcn_mfma_f32_16x16x32_bf16(a[0][ks], b0, acc00, 0, 0, 0);
      acc01 = __builtin_amdgcn_mfma_f32_16x16x32_bf16(a[0][ks], b1, acc01, 0, 0, 0);
      acc10 = __builtin_amdgcn_mfma_f32_16x16x32_bf16(a[1][ks], b0, acc10, 0, 0, 0);
      acc11 = __builtin_amdgcn_mfma_f32_16x16x32_bf16(a[1][ks], b1, acc11, 0, 0, 0);
    }

    float ec0 = 0.f, ec1 = 0.f, bc0 = 0.f, bc1 = 0.f;
    const int j0 = C0 + wc * 32 + n16;
    const int j1 = j0 + 16;

#define EPI(ACC, MM, JN, ECOL, BCOL, ERA, BRA)                        \
  _Pragma("unroll")                                                   \
  for (int r = 0; r < 4; r++) {                                       \
    int row = R0 + wr * 32 + MM * 16 + q * 4 + r;                     \
    float tv = ACC[r] * TEMP_INV;                                     \
    bool valid = (row < M) && (JN < M);                               \
    float e = valid ? __expf(tv - 5.0f) : 0.0f;                       \
    float bv = (valid && JN >= bs[MM][r] && JN < be[MM][r]) ? tv : 0.0f; \
    ERA[r] += e; BRA[r] += bv; ECOL += e; BCOL += bv;                 \
  }
    EPI(acc00, 0, j0, ec0, bc0, er0, br0)
    EPI(acc01, 0, j1, ec1, bc1, er0, br0)
    EPI(acc10, 1, j0, ec0, bc0, er1, br1)
    EPI(acc11, 1, j1, ec1, bc1, er1, br1)
#undef EPI

    // column flush (symmetric counterpart) — off-diagonal tiles only.
    // reduce over q (lane bits 4,5); both wr halves atomically combine.
    if (tj != si) {
      float e = ec0, b = bc0;
      e += __shfl_xor(e, 16); e += __shfl_xor(e, 32);
      b += __shfl_xor(b, 16); b += __shfl_xor(b, 32);
      if (q == 0 && j0 < M) { atomicAdd(&Ep[j0], e); atomicAdd(&Bp[j0], b); }
      e = ec1; b = bc1;
      e += __shfl_xor(e, 16); e += __shfl_xor(e, 32);
      b += __shfl_xor(b, 16); b += __shfl_xor(b, 32);
      if (q == 0 && j1 < M) { atomicAdd(&Ep[j1], e); atomicAdd(&Bp[j1], b); }
    }
  }

  // row flush: reduce over the 16 n16-lanes; both wc halves combine via atomics
#pragma unroll
  for (int mr = 0; mr < 8; mr++) {
    const int m = mr >> 2, r = mr & 3;
    float e = m ? er1[r] : er0[r];
    float b = m ? br1[r] : br0[r];
    for (int msk = 1; msk <= 8; msk <<= 1) { e += __shfl_xor(e, msk); b += __shfl_xor(b, msk); }
    int row = R0 + wr * 32 + m * 16 + q * 4 + r;
    if (n16 == 0 && row < M) {
      atomicAdd(&Ep[row], e);
      atomicAdd(&Bp[row], b);
    }
  }
}

__global__ __launch_bounds__(256) void finalize_kernel(
    const float* __restrict__ partials,
    const float* __restrict__ Esup, const float* __restrict__ Bsup, const float* __restrict__ dsup,
    const float* __restrict__ Euns, const float* __restrict__ Buns, const float* __restrict__ duns,
    int Msup, int Muns, int PV, int P, int NEG, int V, float* __restrict__ out) {
  const int t = threadIdx.x;
  float cnt = 0.f, sm = 0.f, sv[8];
  for (int v = 0; v < 8; v++) sv[v] = 0.f;
  const int Vc = V > 8 ? 8 : V;
  for (int b = t; b < NB_BCE; b += 256) {
    cnt += partials[b * 16 + 0];
    sm  += partials[b * 16 + 1];
    for (int v = 0; v < Vc; v++) sv[v] += partials[b * 16 + 2 + v];
  }
  cnt = block_sum256(cnt);
  sm = block_sum256(sm);
  float svt = 0.f;
  for (int v = 0; v < Vc; v++) svt += block_sum256(sv[v]);
  const float denomC = fmaxf(cnt, 1.0f);
  const float main_loss = sm / denomC;
  const float view_loss = (svt / denomC) / (float)V;

  // sup: per-anchor = log(E - exp(d-5)) + 5 - (B - d)/pos_count
  float ssup = 0.f;
  for (int row = t; row < Msup; row += 256) {
    float E = Esup[row], B = Bsup[row];
    float d = dsup[row];
    float dn = E - __expf(d - 5.0f);
    float cl = (row < PV) ? (float)P : (float)NEG;
    float pc = (float)(V - 1) + (cl - 1.0f) * (float)V;
    ssup += logf(dn) + 5.0f - (B - d) / pc;
  }
  ssup = block_sum256(ssup);
  const float sup_loss = ssup / (float)Msup;

  // unsup: per-anchor = log(E - exp(d-5)) + 5 - (B - d)/(V-1)
  float suns = 0.f;
  for (int row = t; row < Muns; row += 256) {
    float E = Euns[row], B = Buns[row];
    float d = duns[row];
    float dn = E - __expf(d - 5.0f);
    suns += logf(dn) + 5.0f - (B - d) / (float)(V - 1);
  }
  suns = block_sum256(suns);
  const float unsup_loss = suns / (float)Muns;

  if (t == 0) {
    float total = main_loss + view_loss + sup_loss + W_UNSUP * unsup_loss;
    out[0] = total;
    out[1] = main_loss;
    out[2] = view_loss;
    out[3] = sup_loss;
    out[4] = unsup_loss;
  }
}

extern "C" void kernel_launch(void* const* d_in, const int* in_sizes, int n_in,
                              void* d_out, int out_size, void* d_ws, size_t ws_size,
                              hipStream_t stream) {
  const float* fused  = (const float*)d_in[0];
  const float* viewl  = (const float*)d_in[1];
  const float* proj   = (const float*)d_in[2];
  const float* labels = (const float*)d_in[3];
  const void*  maskp  = d_in[4];
  const int* pos_idx  = (const int*)d_in[5];
  const int* neg_idx  = (const int*)d_in[6];
  const int* unl_idx  = (const int*)d_in[7];

  const int N = in_sizes[0];
  const int V = in_sizes[1] / N;
  const int D = in_sizes[2] / in_sizes[1];   // = 256
  const int P = in_sizes[5];
  const int NEG = in_sizes[6];
  const int U = in_sizes[7];
  const int L = P + NEG;
  const int Msup = L * V;
  const int Muns = U * V;
  const int PV = P * V;

  char* ws = (char*)d_ws;
  size_t off = 0;
  auto alloc = [&](size_t bytes) { size_t o = off; off += (bytes + 255) & ~(size_t)255; return o; };
  const size_t o_flag = alloc(4);
  const size_t o_part = alloc((size_t)NB_BCE * 16 * 4);
  const size_t o_zsup = alloc((size_t)Msup * D * 2);
  const size_t o_zuns = alloc((size_t)Muns * D * 2);
  const size_t o_dsup = alloc((size_t)Msup * 4);
  const size_t o_duns = alloc((size_t)Muns * 4);
  const size_t o_Esup = alloc((size_t)Msup * 4);
  const size_t o_Bsup = alloc((size_t)Msup * 4);
  const size_t o_Euns = alloc((size_t)Muns * 4);
  const size_t o_Buns = alloc((size_t)Muns * 4);

  int* flag = (int*)(ws + o_flag);
  float* partials = (float*)(ws + o_part);
  unsigned short* zsup = (unsigned short*)(ws + o_zsup);
  unsigned short* zuns = (unsigned short*)(ws + o_zuns);
  float* dsup = (float*)(ws + o_dsup);
  float* duns = (float*)(ws + o_duns);
  float* Esup = (float*)(ws + o_Esup);
  float* Bsup = (float*)(ws + o_Bsup);
  float* Euns = (float*)(ws + o_Euns);
  float* Buns = (float*)(ws + o_Buns);

  int nw = N / 4 < 256 ? N / 4 : 256;
  detect_kernel<<<1, 256, 0, stream>>>((const unsigned int*)maskp, nw, flag);
  bce_kernel<<<NB_BCE, 256, 0, stream>>>(fused, viewl, labels, maskp, flag, partials, N, V);

  const int Mmax = Msup > Muns ? Msup : Muns;
  dim3 ggrid((Mmax + 7) / 8, 2);
  gather_kernel<<<ggrid, 256, 0, stream>>>(proj, pos_idx, neg_idx, unl_idx,
                                           zsup, zuns, dsup, duns,
                                           Esup, Bsup, Euns, Buns,
                                           N, D, V, P, Msup, Muns);

  const int nsS = (Msup + 63) / 64;
  const int nsU = (Muns + 63) / 64;
  const int nsMax = nsS > nsU ? nsS : nsU;
  dim3 sgrid(nsMax * NSPLIT, 2);
  sim_kernel<<<sgrid, 256, 0, stream>>>(zsup, zuns, Esup, Bsup, Euns, Buns,
                                        Msup, Muns, PV, V, nsS, nsU);

  finalize_kernel<<<1, 256, 0, stream>>>(partials, Esup, Bsup, dsup, Euns, Buns, duns,
                                         Msup, Muns, PV, P, NEG, V, (float*)d_out);
}

// Round 5
// 445.321 us; speedup vs baseline: 1.1151x; 1.0406x over previous
//
#include <hip/hip_runtime.h>
#include <math.h>

typedef short short8 __attribute__((ext_vector_type(8)));
typedef float floatx4 __attribute__((ext_vector_type(4)));

#define TEMP_INV 5.0f
#define W_UNSUP 0.2f
#define NB_BCE 256
#define NSPLIT 8

static __device__ __forceinline__ unsigned short f2bf(float f) {
  unsigned int u = __float_as_uint(f);
  u += 0x7FFFu + ((u >> 16) & 1u);
  return (unsigned short)(u >> 16);
}

__device__ __forceinline__ float block_sum256(float v) {
  __shared__ float sh[4];
  for (int m = 1; m <= 32; m <<= 1) v += __shfl_xor(v, m);
  __syncthreads();
  if ((threadIdx.x & 63) == 0) sh[threadIdx.x >> 6] = v;
  __syncthreads();
  return sh[0] + sh[1] + sh[2] + sh[3];
}

// BCE with in-block mask-storage detection (each block re-scans the same
// nw words -- L2-hot after the first block, ~free; removes a kernel launch).
__global__ __launch_bounds__(256) void bce_kernel(
    const float* __restrict__ fused, const float* __restrict__ viewl,
    const float* __restrict__ labels, const void* __restrict__ maskp,
    float* __restrict__ partials, int N, int V, int nw) {
  __shared__ int s_int, s_flt;
  const int t = threadIdx.x;
  if (t == 0) { s_int = 1; s_flt = 1; }
  __syncthreads();
  {
    const unsigned int* w = (const unsigned int*)maskp;
    int okI = 1, okF = 1;
    for (int i = t; i < nw; i += 256) {
      unsigned int x = w[i];
      if (x != 0u && x != 1u) okI = 0;
      if (x != 0u && x != 0x3F800000u) okF = 0;
    }
    if (!okI) atomicAnd(&s_int, 0);
    if (!okF) atomicAnd(&s_flt, 0);
  }
  __syncthreads();
  const int flag = s_int ? 0 : (s_flt ? 1 : 2);

  float cnt = 0.f, sm = 0.f;
  float sv[8];
  for (int v = 0; v < 8; v++) sv[v] = 0.f;
  const int Vc = V > 8 ? 8 : V;
  for (int i = blockIdx.x * blockDim.x + t; i < N; i += gridDim.x * blockDim.x) {
    bool m;
    if (flag == 0)      m = ((const int*)maskp)[i] != 0;
    else if (flag == 1) m = ((const float*)maskp)[i] != 0.0f;
    else                m = ((const unsigned char*)maskp)[i] != 0;
    if (!m) continue;
    float y = labels[i];
    cnt += 1.0f;
    float x = fused[i];
    sm += fmaxf(x, 0.f) - x * y + log1pf(__expf(-fabsf(x)));
    for (int v = 0; v < Vc; v++) {
      float xv = viewl[(size_t)v * N + i];
      sv[v] += fmaxf(xv, 0.f) - xv * y + log1pf(__expf(-fabsf(xv)));
    }
  }
  float tot = block_sum256(cnt);
  if (t == 0) partials[blockIdx.x * 16 + 0] = tot;
  tot = block_sum256(sm);
  if (t == 0) partials[blockIdx.x * 16 + 1] = tot;
  for (int v = 0; v < Vc; v++) {
    tot = block_sum256(sv[v]);
    if (t == 0) partials[blockIdx.x * 16 + 2 + v] = tot;
  }
}

// Gather rows into bf16 matrices (8 rows/block, 32 lanes/row, 8 elems/lane).
// Also zero-init the atomic E/B accumulators used by sim_kernel.
__global__ __launch_bounds__(256) void gather_kernel(
    const float* __restrict__ proj, const int* __restrict__ pos_idx,
    const int* __restrict__ neg_idx, const int* __restrict__ unl_idx,
    unsigned short* __restrict__ zsup, unsigned short* __restrict__ zuns,
    float* __restrict__ dsup, float* __restrict__ duns,
    float* __restrict__ Esup, float* __restrict__ Bsup,
    float* __restrict__ Euns, float* __restrict__ Buns,
    int N, int D, int V, int P, int Msup, int Muns) {
  const int prob = blockIdx.y;
  const int M = prob ? Muns : Msup;
  const int r0 = blockIdx.x * 8;
  const int t = threadIdx.x;
  if (t < 8) {
    int rz = r0 + t;
    if (rz < M) {
      if (prob) { Euns[rz] = 0.f; Buns[rz] = 0.f; }
      else      { Esup[rz] = 0.f; Bsup[rz] = 0.f; }
    }
  }
  const int sub = t >> 5, ln = t & 31;
  const int r = r0 + sub;
  if (r >= M) return;
  const int l = r / V, v = r - l * V;
  const int idx = prob ? unl_idx[l] : (l < P ? pos_idx[l] : neg_idx[l - P]);
  const float* src = proj + ((size_t)v * N + (size_t)idx) * D + ln * 8;
  floatx4 p0 = *(const floatx4*)(src);
  floatx4 p1 = *(const floatx4*)(src + 4);
  float s = 0.f;
#pragma unroll
  for (int k = 0; k < 4; k++) s += p0[k] * p0[k] + p1[k] * p1[k];
  // reduce over the 32 lanes of this row (masks 1..16 stay inside the 32-group)
  for (int m = 1; m <= 16; m <<= 1) s += __shfl_xor(s, m);
  const float n2 = s;
  float sc = 1.0f, dval = n2 * TEMP_INV;
  if (prob) {
    sc = 1.0f / (sqrtf(n2) + 1e-8f);
    dval = n2 * sc * sc * TEMP_INV;
  }
  short8 vv;
#pragma unroll
  for (int k = 0; k < 4; k++) {
    vv[k]     = (short)f2bf(p0[k] * sc);
    vv[k + 4] = (short)f2bf(p1[k] * sc);
  }
  unsigned short* zd = prob ? zuns : zsup;
  *(short8*)(zd + (size_t)r * 256 + ln * 8) = vv;
  if (ln == 0) (prob ? duns : dsup)[r] = dval;
}

// Symmetric sim kernel, A-amortized + 2-phase reg-prefetch pipeline.
// Block = (row strip si, col split s); loads its 64-row A strip ONCE into
// registers and walks column tiles tj = si+s, si+s+NSPLIT, ... (upper
// triangle). Staging is software-pipelined: next tile's 8x16B global loads
// are issued right after the current tile's ds_writes, so HBM/L2 latency
// hides under the 32-MFMA compute. Row E/B accumulate in registers across
// tiles (one flush/block); column E/B (symmetric counterpart) flush per
// off-diagonal tile via global atomicAdd.
__global__ __launch_bounds__(256) void sim_kernel(
    const unsigned short* __restrict__ zsup, const unsigned short* __restrict__ zuns,
    float* __restrict__ Esup, float* __restrict__ Bsup,
    float* __restrict__ Euns, float* __restrict__ Buns,
    int Msup, int Muns, int PV, int V, int nsSup, int nsUns) {
  const int prob = blockIdx.y;
  const unsigned short* __restrict__ z = prob ? zuns : zsup;
  float* __restrict__ Ep = prob ? Euns : Esup;
  float* __restrict__ Bp = prob ? Buns : Bsup;
  const int M = prob ? Muns : Msup;
  const int ns = prob ? nsUns : nsSup;

  const int si = blockIdx.x / NSPLIT;
  const int s  = blockIdx.x - si * NSPLIT;
  if (si >= ns) return;

  const int R0 = si * 64;
  const int tid = threadIdx.x;
  const int wave = tid >> 6;
  const int wr = wave >> 1, wc = wave & 1;     // row-half / col-half of the 64x64 tile
  const int q = (tid >> 4) & 3;
  const int n16 = tid & 15;

  // 64 col rows x 256 k, +8 bf16 pad per row -> ds_read_b128 is 2-way (free)
  __shared__ __align__(16) unsigned short lds[64 * 264];

  // staging addresses for this thread (8 chunks of 16B)
  const int srow = tid >> 5;             // rows srow, srow+8, ..., srow+56
  const int soff = (tid & 31) * 8;

  // A fragments: 2 sets of 16 rows (this wave's 32 rows), K=256 in registers
  short8 a[2][8];
#pragma unroll
  for (int m = 0; m < 2; m++) {
    int row = R0 + wr * 32 + m * 16 + n16;
    if (row >= M) row = M - 1;
    const unsigned short* zr = z + (size_t)row * 256 + q * 8;
#pragma unroll
    for (int ks = 0; ks < 8; ks++) a[m][ks] = *(const short8*)(zr + ks * 32);
  }

  // positive-block bounds per output row (symmetric predicate)
  int bs[2][4], be[2][4];
#pragma unroll
  for (int m = 0; m < 2; m++)
#pragma unroll
    for (int r = 0; r < 4; r++) {
      int row = R0 + wr * 32 + m * 16 + q * 4 + r;
      if (row >= M) row = M - 1;
      if (prob == 0) { bs[m][r] = row < PV ? 0 : PV; be[m][r] = row < PV ? PV : M; }
      else           { int b0 = (row / V) * V; bs[m][r] = b0; be[m][r] = b0 + V; }
    }

  // row accumulators persist across all tiles of this block
  float er0[4] = {0, 0, 0, 0}, er1[4] = {0, 0, 0, 0};
  float br0[4] = {0, 0, 0, 0}, br1[4] = {0, 0, 0, 0};

  // prologue: prefetch first tile into registers
  short8 cur[8];
  int tj = si + s;
  if (tj < ns) {
    const int C0 = tj * 64;
#pragma unroll
    for (int cc = 0; cc < 8; cc++) {
      int gcol = C0 + srow + cc * 8;
      short8 vv = {0, 0, 0, 0, 0, 0, 0, 0};
      if (gcol < M) vv = *(const short8*)(z + (size_t)gcol * 256 + soff);
      cur[cc] = vv;
    }
  }

  for (; tj < ns; tj += NSPLIT) {
    const int C0 = tj * 64;
    __syncthreads();        // previous tile's ds_reads complete
    // write current tile to LDS (ds_write reads regs at issue -> cur reusable)
#pragma unroll
    for (int cc = 0; cc < 8; cc++)
      *(short8*)(&lds[(srow + cc * 8) * 264 + soff]) = cur[cc];
    // issue next tile's global loads; they complete under this tile's compute
    {
      int tjn = tj + NSPLIT;
      if (tjn < ns) {
        const int C0n = tjn * 64;
#pragma unroll
        for (int cc = 0; cc < 8; cc++) {
          int gcol = C0n + srow + cc * 8;
          short8 vv = {0, 0, 0, 0, 0, 0, 0, 0};
          if (gcol < M) vv = *(const short8*)(z + (size_t)gcol * 256 + soff);
          cur[cc] = vv;
        }
      }
    }
    __syncthreads();        // LDS tile ready

    floatx4 acc00 = {0.f, 0.f, 0.f, 0.f}, acc01 = {0.f, 0.f, 0.f, 0.f};
    floatx4 acc10 = {0.f, 0.f, 0.f, 0.f}, acc11 = {0.f, 0.f, 0.f, 0.f};
#pragma unroll
    for (int ks = 0; ks < 8; ks++) {
      const unsigned short* bp = &lds[(wc * 32 + n16) * 264 + q * 8 + ks * 32];
      short8 b0 = *(const short8*)bp;
      short8 b1 = *(const short8*)(bp + 16 * 264);
      acc00 = __builtin_amdgcn_mfma_f32_16x16x32_bf16(a[0][ks], b0, acc00, 0, 0, 0);
      acc01 = __builtin_amdgcn_mfma_f32_16x16x32_bf16(a[0][ks], b1, acc01, 0, 0, 0);
      acc10 = __builtin_amdgcn_mfma_f32_16x16x32_bf16(a[1][ks], b0, acc10, 0, 0, 0);
      acc11 = __builtin_amdgcn_mfma_f32_16x16x32_bf16(a[1][ks], b1, acc11, 0, 0, 0);
    }

    float ec0 = 0.f, ec1 = 0.f, bc0 = 0.f, bc1 = 0.f;
    const int j0 = C0 + wc * 32 + n16;
    const int j1 = j0 + 16;

#define EPI(ACC, MM, JN, ECOL, BCOL, ERA, BRA)                        \
  _Pragma("unroll")                                                   \
  for (int r = 0; r < 4; r++) {                                       \
    int row = R0 + wr * 32 + MM * 16 + q * 4 + r;                     \
    float tv = ACC[r] * TEMP_INV;                                     \
    bool valid = (row < M) && (JN < M);                               \
    float e = valid ? __expf(tv - 5.0f) : 0.0f;                       \
    float bv = (valid && JN >= bs[MM][r] && JN < be[MM][r]) ? tv : 0.0f; \
    ERA[r] += e; BRA[r] += bv; ECOL += e; BCOL += bv;                 \
  }
    EPI(acc00, 0, j0, ec0, bc0, er0, br0)
    EPI(acc01, 0, j1, ec1, bc1, er0, br0)
    EPI(acc10, 1, j0, ec0, bc0, er1, br1)
    EPI(acc11, 1, j1, ec1, bc1, er1, br1)
#undef EPI

    // column flush (symmetric counterpart) — off-diagonal tiles only.
    if (tj != si) {
      float e = ec0, b = bc0;
      e += __shfl_xor(e, 16); e += __shfl_xor(e, 32);
      b += __shfl_xor(b, 16); b += __shfl_xor(b, 32);
      if (q == 0 && j0 < M) { atomicAdd(&Ep[j0], e); atomicAdd(&Bp[j0], b); }
      e = ec1; b = bc1;
      e += __shfl_xor(e, 16); e += __shfl_xor(e, 32);
      b += __shfl_xor(b, 16); b += __shfl_xor(b, 32);
      if (q == 0 && j1 < M) { atomicAdd(&Ep[j1], e); atomicAdd(&Bp[j1], b); }
    }
  }

  // row flush: reduce over the 16 n16-lanes; both wc halves combine via atomics
#pragma unroll
  for (int mr = 0; mr < 8; mr++) {
    const int m = mr >> 2, r = mr & 3;
    float e = m ? er1[r] : er0[r];
    float b = m ? br1[r] : br0[r];
    for (int msk = 1; msk <= 8; msk <<= 1) { e += __shfl_xor(e, msk); b += __shfl_xor(b, msk); }
    int row = R0 + wr * 32 + m * 16 + q * 4 + r;
    if (n16 == 0 && row < M) {
      atomicAdd(&Ep[row], e);
      atomicAdd(&Bp[row], b);
    }
  }
}

__global__ __launch_bounds__(256) void finalize_kernel(
    const float* __restrict__ partials,
    const float* __restrict__ Esup, const float* __restrict__ Bsup, const float* __restrict__ dsup,
    const float* __restrict__ Euns, const float* __restrict__ Buns, const float* __restrict__ duns,
    int Msup, int Muns, int PV, int P, int NEG, int V, float* __restrict__ out) {
  const int t = threadIdx.x;
  float cnt = 0.f, sm = 0.f, sv[8];
  for (int v = 0; v < 8; v++) sv[v] = 0.f;
  const int Vc = V > 8 ? 8 : V;
  for (int b = t; b < NB_BCE; b += 256) {
    cnt += partials[b * 16 + 0];
    sm  += partials[b * 16 + 1];
    for (int v = 0; v < Vc; v++) sv[v] += partials[b * 16 + 2 + v];
  }
  cnt = block_sum256(cnt);
  sm = block_sum256(sm);
  float svt = 0.f;
  for (int v = 0; v < Vc; v++) svt += block_sum256(sv[v]);
  const float denomC = fmaxf(cnt, 1.0f);
  const float main_loss = sm / denomC;
  const float view_loss = (svt / denomC) / (float)V;

  // sup: per-anchor = log(E - exp(d-5)) + 5 - (B - d)/pos_count
  float ssup = 0.f;
  for (int row = t; row < Msup; row += 256) {
    float E = Esup[row], B = Bsup[row];
    float d = dsup[row];
    float dn = E - __expf(d - 5.0f);
    float cl = (row < PV) ? (float)P : (float)NEG;
    float pc = (float)(V - 1) + (cl - 1.0f) * (float)V;
    ssup += logf(dn) + 5.0f - (B - d) / pc;
  }
  ssup = block_sum256(ssup);
  const float sup_loss = ssup / (float)Msup;

  // unsup: per-anchor = log(E - exp(d-5)) + 5 - (B - d)/(V-1)
  float suns = 0.f;
  for (int row = t; row < Muns; row += 256) {
    float E = Euns[row], B = Buns[row];
    float d = duns[row];
    float dn = E - __expf(d - 5.0f);
    suns += logf(dn) + 5.0f - (B - d) / (float)(V - 1);
  }
  suns = block_sum256(suns);
  const float unsup_loss = suns / (float)Muns;

  if (t == 0) {
    float total = main_loss + view_loss + sup_loss + W_UNSUP * unsup_loss;
    out[0] = total;
    out[1] = main_loss;
    out[2] = view_loss;
    out[3] = sup_loss;
    out[4] = unsup_loss;
  }
}

extern "C" void kernel_launch(void* const* d_in, const int* in_sizes, int n_in,
                              void* d_out, int out_size, void* d_ws, size_t ws_size,
                              hipStream_t stream) {
  const float* fused  = (const float*)d_in[0];
  const float* viewl  = (const float*)d_in[1];
  const float* proj   = (const float*)d_in[2];
  const float* labels = (const float*)d_in[3];
  const void*  maskp  = d_in[4];
  const int* pos_idx  = (const int*)d_in[5];
  const int* neg_idx  = (const int*)d_in[6];
  const int* unl_idx  = (const int*)d_in[7];

  const int N = in_sizes[0];
  const int V = in_sizes[1] / N;
  const int D = in_sizes[2] / in_sizes[1];   // = 256
  const int P = in_sizes[5];
  const int NEG = in_sizes[6];
  const int U = in_sizes[7];
  const int L = P + NEG;
  const int Msup = L * V;
  const int Muns = U * V;
  const int PV = P * V;

  char* ws = (char*)d_ws;
  size_t off = 0;
  auto alloc = [&](size_t bytes) { size_t o = off; off += (bytes + 255) & ~(size_t)255; return o; };
  const size_t o_part = alloc((size_t)NB_BCE * 16 * 4);
  const size_t o_zsup = alloc((size_t)Msup * D * 2);
  const size_t o_zuns = alloc((size_t)Muns * D * 2);
  const size_t o_dsup = alloc((size_t)Msup * 4);
  const size_t o_duns = alloc((size_t)Muns * 4);
  const size_t o_Esup = alloc((size_t)Msup * 4);
  const size_t o_Bsup = alloc((size_t)Msup * 4);
  const size_t o_Euns = alloc((size_t)Muns * 4);
  const size_t o_Buns = alloc((size_t)Muns * 4);

  float* partials = (float*)(ws + o_part);
  unsigned short* zsup = (unsigned short*)(ws + o_zsup);
  unsigned short* zuns = (unsigned short*)(ws + o_zuns);
  float* dsup = (float*)(ws + o_dsup);
  float* duns = (float*)(ws + o_duns);
  float* Esup = (float*)(ws + o_Esup);
  float* Bsup = (float*)(ws + o_Bsup);
  float* Euns = (float*)(ws + o_Euns);
  float* Buns = (float*)(ws + o_Buns);

  int nw = N / 4 < 256 ? N / 4 : 256;
  bce_kernel<<<NB_BCE, 256, 0, stream>>>(fused, viewl, labels, maskp, partials, N, V, nw);

  const int Mmax = Msup > Muns ? Msup : Muns;
  dim3 ggrid((Mmax + 7) / 8, 2);
  gather_kernel<<<ggrid, 256, 0, stream>>>(proj, pos_idx, neg_idx, unl_idx,
                                           zsup, zuns, dsup, duns,
                                           Esup, Bsup, Euns, Buns,
                                           N, D, V, P, Msup, Muns);

  const int nsS = (Msup + 63) / 64;
  const int nsU = (Muns + 63) / 64;
  const int nsMax = nsS > nsU ? nsS : nsU;
  dim3 sgrid(nsMax * NSPLIT, 2);
  sim_kernel<<<sgrid, 256, 0, stream>>>(zsup, zuns, Esup, Bsup, Euns, Buns,
                                        Msup, Muns, PV, V, nsS, nsU);

  finalize_kernel<<<1, 256, 0, stream>>>(partials, Esup, Bsup, dsup, Euns, Buns, duns,
                                         Msup, Muns, PV, P, NEG, V, (float*)d_out);
}